// Round 15
// baseline (129.973 us; speedup 1.0000x reference)
//
#include <hip/hip_runtime.h>
#include <math.h>

// ---------------------------------------------------------------------------
// MegaCartTensorOut, R15: FUSED gemm+tail (single main kernel).
// R14 counters: gemm_full 65us was bound by the yall/tww ws round-trip
// (58MB write + 58MB read, 1.85 TB/s). The split only existed because fused
// kernels hit register pathologies; R13 proved the trigger was cg-in-LDS
// broadcast fodder (SGPR-CG: VGPR 256->40). So: fuse, keep yall/tw in LDS
// (39.9KB), CG via SGPR loads, unroll-1 tail loop, 9-lane cart epilogue.
// Tripwire: VGPR ~250 => fodder back, revert to R14 split.
// ---------------------------------------------------------------------------

#define N_CG_FLOATS 438

typedef short s16x8 __attribute__((ext_vector_type(8)));
typedef short s16x4 __attribute__((ext_vector_type(4)));
typedef float f32x4 __attribute__((ext_vector_type(4)));

// pk region (units: shorts, from byte 2048 of ws) — ends at byte 69632
#define PK_BYTE_OFF 2048
#define PK_A1 0       // 16 frags (K=128,N=64)
#define PK_W0 8192    // 8  frags (K=128,N=32), *1/sqrt(128)
#define PK_A2 12288   // 36 frags (K=64, N=288)
#define PK_W1 30720   // 4  frags (K=64, N=32), *0.125
#define PK_W2 32768   // 2  frags (K=32, N=32), *1/sqrt(32)
#define PK_TOTAL 33792

__device__ __forceinline__ short f2bf(float f) {
  union { float f; unsigned u; } x; x.f = f;
  unsigned r = (x.u + 0x7FFFu + ((x.u >> 16) & 1u)) >> 16;
  return (short)r;
}
__device__ __forceinline__ float bf2f(unsigned short s) {
  union { unsigned u; float f; } x; x.u = ((unsigned)s) << 16;
  return x.f;
}

// ---------------- CG setup (verified rounds 1-14) ----------------------------

__device__ __forceinline__ double dfact(int n) {
  double r = 1.0;
  for (int i = 2; i <= n; ++i) r *= (double)i;
  return r;
}

__device__ __forceinline__ void u_elem(int l, int i, int j, double& re, double& im) {
  re = 0.0; im = 0.0;
  const int mr = i - l, mc = j - l;
  const double is2 = 0.70710678118654752440;
  if (mr == 0) { if (mc == 0) re = 1.0; }
  else if (mr > 0) {
    if (mc == mr) re = ((mr & 1) ? -1.0 : 1.0) * is2;
    else if (mc == -mr) re = is2;
  } else {
    int m = -mr;
    if (mc == m) im = -(((m & 1) ? -1.0 : 1.0)) * is2;
    else if (mc == -m) im = is2;
  }
}

__global__ void setup_cg_par(float* __restrict__ ws) {
  const int LAs[12] = {0, 1, 2, 1, 2, 0, 2, 1, 2, 1, 1, 1};
  const int LBs[12] = {0, 1, 2, 1, 2, 2, 0, 1, 2, 1, 1, 1};
  const int LOs[12] = {0, 0, 0, 1, 1, 2, 2, 2, 2, 0, 1, 2};
  const int OFF[12] = {0, 1, 10, 35, 62, 137, 162, 187, 232, 357, 366, 393};

  const int blk = blockIdx.x;
  const int l1 = LAs[blk], l2 = LBs[blk], l3 = LOs[blk];
  const double scale = (blk >= 9) ? sqrt(2.0 * l3 + 1.0) : 1.0;
  const int n1 = 2 * l1 + 1, n2 = 2 * l2 + 1, n3 = 2 * l3 + 1;
  const int nel = n1 * n2 * n3;
  const int t = threadIdx.x;

  __shared__ double Cs[125];
  __shared__ double Rre[125], Rim[125];
  __shared__ double s_inv;
  __shared__ int s_useRe;

  if (t < nel) {
    const int i3 = t % n3, i2 = (t / n3) % n2, i1 = t / (n3 * n2);
    const int m1 = i1 - l1, m2 = i2 - l2, m3 = i3 - l3;
    double val = 0.0;
    if (m1 + m2 == m3) {
      double pre = sqrt((2.0 * l3 + 1.0) * dfact(l1 + l2 - l3) * dfact(l1 - l2 + l3) *
                        dfact(-l1 + l2 + l3) / dfact(l1 + l2 + l3 + 1));
      pre *= sqrt(dfact(l3 + m3) * dfact(l3 - m3) * dfact(l1 - m1) * dfact(l1 + m1) *
                  dfact(l2 - m2) * dfact(l2 + m2));
      double s = 0.0;
      for (int k = 0; k <= l1 + l2 - l3; ++k) {
        int d1 = l1 + l2 - l3 - k, d2 = l1 - m1 - k, d3 = l2 + m2 - k;
        int d4 = l3 - l2 + m1 + k, d5 = l3 - l1 - m2 + k;
        if (d1 < 0 || d2 < 0 || d3 < 0 || d4 < 0 || d5 < 0) continue;
        double prod = dfact(k) * dfact(d1) * dfact(d2) * dfact(d3) * dfact(d4) * dfact(d5);
        s += ((k & 1) ? -1.0 : 1.0) / prod;
      }
      val = pre * s;
    }
    Cs[t] = val;
  }
  __syncthreads();

  if (t < nel) {
    const int c = t % n3, bb = (t / n3) % n2, a = t / (n3 * n2);
    double sr_ = 0.0, si_ = 0.0;
    for (int m = 0; m < n1; ++m) {
      double u1r, u1i;
      u_elem(l1, a, m, u1r, u1i);
      if (u1r == 0.0 && u1i == 0.0) continue;
      for (int nn = 0; nn < n2; ++nn) {
        double u2r, u2i;
        u_elem(l2, bb, nn, u2r, u2i);
        double t12r = u1r * u2r - u1i * u2i;
        double t12i = u1r * u2i + u1i * u2r;
        if (t12r == 0.0 && t12i == 0.0) continue;
        for (int o = 0; o < n3; ++o) {
          double cgv = Cs[(m * n2 + nn) * n3 + o];
          if (cgv == 0.0) continue;
          double u3r, u3i;
          u_elem(l3, c, o, u3r, u3i);
          sr_ += (t12r * u3r + t12i * u3i) * cgv;
          si_ += (t12i * u3r - t12r * u3i) * cgv;
        }
      }
    }
    Rre[t] = sr_;
    Rim[t] = si_;
  }
  __syncthreads();

  if (t == 0) {
    double maxRe = 0.0, maxIm = 0.0;
    for (int e = 0; e < nel; ++e) {
      maxRe = fmax(maxRe, fabs(Rre[e]));
      maxIm = fmax(maxIm, fabs(Rim[e]));
    }
    int useRe = (maxRe >= maxIm) ? 1 : 0;
    double nrm = 0.0;
    for (int e = 0; e < nel; ++e) {
      double vv = useRe ? Rre[e] : Rim[e];
      nrm += vv * vv;
    }
    s_useRe = useRe;
    s_inv = scale / sqrt(nrm);
  }
  __syncthreads();

  if (t < nel) {
    double vv = s_useRe ? Rre[t] : Rim[t];
    ws[OFF[blk] + t] = (float)(vv * s_inv);
  }
}

// ---------------- weight fragment packing ------------------------------------
__global__ void pack_weights(const float* __restrict__ A1, const float* __restrict__ W0,
                             const float* __restrict__ A2, const float* __restrict__ W1,
                             const float* __restrict__ W2, float* __restrict__ ws) {
  unsigned short* pk = (unsigned short*)((char*)ws + PK_BYTE_OFF);
  int e = blockIdx.x * 256 + threadIdx.x;
  if (e >= PK_TOTAL) return;
  const float* src;
  int Ncols, off;
  float scale;
  if (e < PK_W0)      { src = A1; Ncols = 64;  off = PK_A1; scale = 1.f; }
  else if (e < PK_A2) { src = W0; Ncols = 32;  off = PK_W0; scale = 0.08838834764831845f; }
  else if (e < PK_W1) { src = A2; Ncols = 288; off = PK_A2; scale = 1.f; }
  else if (e < PK_W2) { src = W1; Ncols = 32;  off = PK_W1; scale = 0.125f; }
  else                { src = W2; Ncols = 32;  off = PK_W2; scale = 0.17677669529663687f; }
  int local = e - off;
  int frag = local >> 9;
  int l = (local >> 3) & 63;
  int j = local & 7;
  int ntn = Ncols >> 4;
  int kt = frag / ntn, nt = frag - kt * ntn;
  int k = kt * 32 + 8 * (l >> 4) + j;
  int c = nt * 16 + (l & 15);
  pk[e] = (unsigned short)f2bf(src[k * Ncols + c] * scale);
}

// ---------------- shared helpers ---------------------------------------------

__device__ __forceinline__ s16x8 cvt8(const float* __restrict__ g) {
  float4 a = *(const float4*)g;
  float4 b = *(const float4*)(g + 4);
  s16x8 r;
  r[0] = f2bf(a.x); r[1] = f2bf(a.y); r[2] = f2bf(a.z); r[3] = f2bf(a.w);
  r[4] = f2bf(b.x); r[5] = f2bf(b.y); r[6] = f2bf(b.z); r[7] = f2bf(b.w);
  return r;
}

__device__ __forceinline__ void sw_wr8(char* sm, int base, int strideB, int r, int c0, s16x8 v) {
  int byte = base + r * strideB + c0 * 2;
  byte ^= (r & 7) << 4;
  *(s16x8*)(sm + byte) = v;
}
__device__ __forceinline__ s16x8 sw_lda16(const char* sm, int base, int strideB, int k0,
                                          int lane) {
  int r = lane & 15;
  int byte = base + r * strideB + (k0 + 8 * (lane >> 4)) * 2;
  byte ^= (r & 7) << 4;
  return *(const s16x8*)(sm + byte);
}

template <int LA, int LB, int LO>
__device__ __forceinline__ void tp_accum(const float* __restrict__ R, float w,
                                         const float* xa, const float* xb, float* sph) {
  constexpr int NA = 2 * LA + 1, NB = 2 * LB + 1, NC = 2 * LO + 1;
#pragma unroll
  for (int a = 0; a < NA; ++a) {
#pragma unroll
    for (int b = 0; b < NB; ++b) {
      float xab = xa[a] * xb[b] * w;
#pragma unroll
      for (int c = 0; c < NC; ++c) sph[c] = fmaf(xab, R[(a * NB + b) * NC + c], sph[c]);
    }
  }
}

// ================== fused main kernel ========================================
// LDS layout (bytes), 39936 total (<40KB):
#define F_XS 0      // [16][128] bf16, 256B rows, swz
#define F_SP 4096   // [16][128] bf16, 256B rows, swz
#define F_H  8192   // [16][64]  bf16, 128B rows, swz
#define F_P1 10240  // 3 planes x [16] rows x 128B, swz
#define F_P2 16384  // 5 planes x [16] rows x 64B, swz
#define F_YA 21504  // [16][288] bf16 linear (576B rows)
#define F_TW 30720  // [16][288] bf16 linear
#define F_SMEM 39936

__global__ __launch_bounds__(256) void mega_fused(
    const float* __restrict__ xs_g, const float* __restrict__ sp_g,
    const int* __restrict__ batch, const float* __restrict__ b1,
    const float* __restrict__ b2, const float* __restrict__ p0,
    const float* __restrict__ p1, const float* __restrict__ p2,
    const float* __restrict__ ws, float* __restrict__ out, int N) {
  __shared__ char sm[F_SMEM];
  const unsigned short* pk = (const unsigned short*)((const char*)ws + PK_BYTE_OFF);
  const float* cg = ws;  // uniform base -> s_load (R13-proven anti-hoist)

  const int t = threadIdx.x;
  const int b0 = blockIdx.x * 16;
  const int lane = t & 63;
  const int wid = t >> 6;

  // ---- staging: xs + sp0 (b128 swz writes)
  {
    int n = t >> 4, c0 = (t & 15) * 8;
    long nn = min((long)(b0 + n), (long)N - 1);
    sw_wr8(sm, F_XS, 256, n, c0, cvt8(xs_g + nn * 128 + c0));
    sw_wr8(sm, F_SP, 256, n, c0, cvt8(sp_g + nn * 480 + c0));
  }
  // ---- staging: l1 planes (4 u's per thread)
  {
    int n = t >> 4, uc = t & 15;
    long nn = min((long)(b0 + n), (long)N - 1);
    const float* g = sp_g + nn * 480 + 128 + uc * 12;
    float4 a0 = *(const float4*)(g), a1 = *(const float4*)(g + 4), a2 = *(const float4*)(g + 8);
    float fl[12] = {a0.x, a0.y, a0.z, a0.w, a1.x, a1.y, a1.z, a1.w, a2.x, a2.y, a2.z, a2.w};
#pragma unroll
    for (int m = 0; m < 3; ++m) {
      s16x4 e;
#pragma unroll
      for (int j = 0; j < 4; ++j) e[j] = f2bf(fl[j * 3 + m]);
      int byte = F_P1 + m * 2048 + n * 128 + uc * 8;
      byte ^= (n & 7) << 4;
      *(s16x4*)(sm + byte) = e;
    }
  }
  // ---- staging: l2 planes (threads < 128, 4 u's per thread)
  if (t < 128) {
    int n = t >> 3, uc = t & 7;
    long nn = min((long)(b0 + n), (long)N - 1);
    const float* g = sp_g + nn * 480 + 320 + uc * 20;
    float4 a0 = *(const float4*)(g), a1 = *(const float4*)(g + 4), a2 = *(const float4*)(g + 8),
           a3 = *(const float4*)(g + 12), a4 = *(const float4*)(g + 16);
    float fl[20] = {a0.x, a0.y, a0.z, a0.w, a1.x, a1.y, a1.z, a1.w, a2.x, a2.y,
                    a2.z, a2.w, a3.x, a3.y, a3.z, a3.w, a4.x, a4.y, a4.z, a4.w};
#pragma unroll
    for (int m = 0; m < 5; ++m) {
      s16x4 e;
#pragma unroll
      for (int j = 0; j < 4; ++j) e[j] = f2bf(fl[j * 5 + m]);
      int byte = F_P2 + m * 1024 + n * 64 + uc * 8;
      byte ^= (n & 7) << 4;
      *(s16x4*)(sm + byte) = e;
    }
  }
  __syncthreads();

  // ---- phase A: h GEMM + y0/y1/y2 tiles -> LDS
  {
    f32x4 acc = {0.f, 0.f, 0.f, 0.f};
#pragma unroll
    for (int kt = 0; kt < 4; ++kt) {
      s16x8 a = sw_lda16(sm, F_XS, 256, kt * 32, lane);
      s16x8 b = *(const s16x8*)(pk + PK_A1 + (((kt << 2) + wid) * 64 + lane) * 8);
      acc = __builtin_amdgcn_mfma_f32_16x16x32_bf16(a, b, acc, 0, 0, 0);
    }
    const int col = wid * 16 + (lane & 15);
    const int r0 = (lane >> 4) * 4;
    const float bb = b1[col];
#pragma unroll
    for (int q = 0; q < 4; ++q) {
      float hv = acc[q] + bb;
      hv = hv / (1.f + __expf(-hv));
      int r = r0 + q;
      int byte = F_H + r * 128 + col * 2;
      byte ^= (r & 7) << 4;
      *(short*)(sm + byte) = f2bf(hv);
    }
  }

  const int r0 = (lane >> 4) * 4;
  if (wid < 2) {  // y0 -> YA cols 0..31
    f32x4 acc = {0.f, 0.f, 0.f, 0.f};
#pragma unroll
    for (int kt = 0; kt < 4; ++kt) {
      s16x8 a = sw_lda16(sm, F_SP, 256, kt * 32, lane);
      s16x8 b = *(const s16x8*)(pk + PK_W0 + (((kt << 1) + wid) * 64 + lane) * 8);
      acc = __builtin_amdgcn_mfma_f32_16x16x32_bf16(a, b, acc, 0, 0, 0);
    }
    const int col = wid * 16 + (lane & 15);
#pragma unroll
    for (int q = 0; q < 4; ++q)
      *(short*)(sm + F_YA + (r0 + q) * 576 + col * 2) = f2bf(acc[q]);
  }
  for (int tl = wid; tl < 6; tl += 4) {  // y1 -> YA cols 32..127
    const int m = tl >> 1, nt = tl & 1;
    f32x4 acc = {0.f, 0.f, 0.f, 0.f};
#pragma unroll
    for (int kt = 0; kt < 2; ++kt) {
      s16x8 a = sw_lda16(sm, F_P1 + m * 2048, 128, kt * 32, lane);
      s16x8 b = *(const s16x8*)(pk + PK_W1 + (((kt << 1) + nt) * 64 + lane) * 8);
      acc = __builtin_amdgcn_mfma_f32_16x16x32_bf16(a, b, acc, 0, 0, 0);
    }
    const int col = 32 + m * 32 + nt * 16 + (lane & 15);
#pragma unroll
    for (int q = 0; q < 4; ++q)
      *(short*)(sm + F_YA + (r0 + q) * 576 + col * 2) = f2bf(acc[q]);
  }
  for (int tl = wid; tl < 10; tl += 4) {  // y2 -> YA cols 128..287
    const int m = tl >> 1, nt = tl & 1;
    f32x4 acc = {0.f, 0.f, 0.f, 0.f};
    {
      s16x8 a = sw_lda16(sm, F_P2 + m * 1024, 64, 0, lane);
      s16x8 b = *(const s16x8*)(pk + PK_W2 + (nt * 64 + lane) * 8);
      acc = __builtin_amdgcn_mfma_f32_16x16x32_bf16(a, b, acc, 0, 0, 0);
    }
    const int col = 128 + m * 32 + nt * 16 + (lane & 15);
#pragma unroll
    for (int q = 0; q < 4; ++q)
      *(short*)(sm + F_YA + (r0 + q) * 576 + col * 2) = f2bf(acc[q]);
  }
  __syncthreads();  // H + YA ready

  // ---- phase B: tw = h @ A2 + b2 -> TW LDS
  for (int tl = wid; tl < 18; tl += 4) {
    f32x4 acc = {0.f, 0.f, 0.f, 0.f};
#pragma unroll
    for (int kt = 0; kt < 2; ++kt) {
      s16x8 a = sw_lda16(sm, F_H, 128, kt * 32, lane);
      s16x8 b = *(const s16x8*)(pk + PK_A2 + ((kt * 18 + tl) * 64 + lane) * 8);
      acc = __builtin_amdgcn_mfma_f32_16x16x32_bf16(a, b, acc, 0, 0, 0);
    }
    const int col = tl * 16 + (lane & 15);
    const float bb = b2[col];
#pragma unroll
    for (int q = 0; q < 4; ++q)
      *(short*)(sm + F_TW + (r0 + q) * 576 + col * 2) = f2bf(acc[q] + bb);
  }
  __syncthreads();

  // ---- phase C: RMS + TP + cart + segment-sum (CG via SGPR global loads)
  const int v = t & 31;
  const int sl = t >> 5;
  const float invs32 = 0.17677669529663687f;
  const float k0c = invs32 / 3.0f;
  const float k1c = 1.7320508075688772f * invs32 / 2.0f;
  const float k2c = 2.23606797749979f * invs32 / 4.0f;
  const float c0 = k0c * p0[0], c1 = k0c * p0[1], c2 = k0c * p0[2];
  const float c3 = k1c * p1[0], c4 = k1c * p1[1];
  const float c5 = k2c * p2[0], c6 = k2c * p2[1], c7 = k2c * p2[2], c8 = k2c * p2[3];
  const float* qb0 = cg + 357;
  const float* qb1 = cg + 366;
  const float* qb2 = cg + 393;

#pragma unroll 1
  for (int r = 0; r < 2; ++r) {
    const int nrow = sl + 8 * r;
    const int n = b0 + nrow;
    const unsigned short* yb = (const unsigned short*)(sm + F_YA + nrow * 576);
    const unsigned short* tb = (const unsigned short*)(sm + F_TW + nrow * 576);

    const float y0v = bf2f(yb[v]);
    float y1[3], y2[5];
#pragma unroll
    for (int m = 0; m < 3; ++m) y1[m] = bf2f(yb[32 + m * 32 + v]);
#pragma unroll
    for (int m = 0; m < 5; ++m) y2[m] = bf2f(yb[128 + m * 32 + v]);

    float s0 = y0v * y0v;
    float s1 = y1[0] * y1[0] + y1[1] * y1[1] + y1[2] * y1[2];
    float s2 = 0.f;
#pragma unroll
    for (int m = 0; m < 5; ++m) s2 = fmaf(y2[m], y2[m], s2);
#pragma unroll
    for (int msk = 16; msk >= 1; msk >>= 1) {
      s0 += __shfl_xor(s0, msk);
      s1 += __shfl_xor(s1, msk);
      s2 += __shfl_xor(s2, msk);
    }
    const float i0 = 1.0f / sqrtf(s0 * (1.0f / 32.0f) + 1e-5f);
    const float i1 = 1.0f / sqrtf(s1 * (1.0f / 96.0f) + 1e-5f);
    const float i2 = 1.0f / sqrtf(s2 * (1.0f / 160.0f) + 1e-5f);
    float xs0[1] = {y0v * i0};
    float xs1[3], xs2[5];
#pragma unroll
    for (int m = 0; m < 3; ++m) xs1[m] = y1[m] * i1;
#pragma unroll
    for (int m = 0; m < 5; ++m) xs2[m] = y2[m] * i2;

    float w9[9];
#pragma unroll
    for (int i = 0; i < 9; ++i) w9[i] = bf2f(tb[i * 32 + v]);

    float sph0[1] = {0.f};
    float sph1[3] = {0.f, 0.f, 0.f};
    float sph2[5] = {0.f, 0.f, 0.f, 0.f, 0.f};
    tp_accum<0, 0, 0>(cg + 0,   w9[0] * c0, xs0, xs0, sph0);
    tp_accum<1, 1, 0>(cg + 1,   w9[1] * c1, xs1, xs1, sph0);
    tp_accum<2, 2, 0>(cg + 10,  w9[2] * c2, xs2, xs2, sph0);
    tp_accum<1, 1, 1>(cg + 35,  w9[3] * c3, xs1, xs1, sph1);
    tp_accum<2, 2, 1>(cg + 62,  w9[4] * c4, xs2, xs2, sph1);
    tp_accum<0, 2, 2>(cg + 137, w9[5] * c5, xs0, xs2, sph2);
    tp_accum<2, 0, 2>(cg + 162, w9[6] * c6, xs2, xs0, sph2);
    tp_accum<1, 1, 2>(cg + 187, w9[7] * c7, xs1, xs1, sph2);
    tp_accum<2, 2, 2>(cg + 232, w9[8] * c8, xs2, xs2, sph2);

#pragma unroll
    for (int msk = 16; msk >= 1; msk >>= 1) {
      sph0[0] += __shfl_xor(sph0[0], msk);
#pragma unroll
      for (int m = 0; m < 3; ++m) sph1[m] += __shfl_xor(sph1[m], msk);
#pragma unroll
      for (int m = 0; m < 5; ++m) sph2[m] += __shfl_xor(sph2[m], msk);
    }

    // cart: lanes 0..8 each compute one (i,j) — sums live in ALL lanes
    if (v < 9 && n < N) {
      const int i = v / 3, j = v - 3 * i;
      float val = sph0[0] * qb0[v];
#pragma unroll
      for (int m = 0; m < 3; ++m) val = fmaf(sph1[m], qb1[v * 3 + m], val);
#pragma unroll
      for (int m = 0; m < 5; ++m) val = fmaf(sph2[m], qb2[v * 5 + m], val);
      float* og = out + (long)batch[n] * 9;
      atomicAdd(&og[((i + 1) % 3) * 3 + ((j + 1) % 3)], val);
    }
  }
}

// ---------------------------------------------------------------------------

extern "C" void kernel_launch(void* const* d_in, const int* in_sizes, int n_in,
                              void* d_out, int out_size, void* d_ws, size_t ws_size,
                              hipStream_t stream) {
  const float* x_scalar = (const float*)d_in[0];
  const float* x_sph    = (const float*)d_in[1];
  const int*   batch    = (const int*)d_in[2];
  const float* W0 = (const float*)d_in[4];
  const float* W1 = (const float*)d_in[5];
  const float* W2 = (const float*)d_in[6];
  const float* A1 = (const float*)d_in[7];
  const float* b1 = (const float*)d_in[8];
  const float* A2 = (const float*)d_in[9];
  const float* b2 = (const float*)d_in[10];
  const float* p0 = (const float*)d_in[11];
  const float* p1 = (const float*)d_in[12];
  const float* p2 = (const float*)d_in[13];
  float* out = (float*)d_out;
  float* ws  = (float*)d_ws;

  const int N = in_sizes[0] / 128;

  hipMemsetAsync(d_out, 0, (size_t)out_size * sizeof(float), stream);
  setup_cg_par<<<12, 128, 0, stream>>>(ws);
  pack_weights<<<(PK_TOTAL + 255) / 256, 256, 0, stream>>>(A1, W0, A2, W1, W2, ws);
  const int blocks = (N + 15) / 16;
  mega_fused<<<blocks, 256, 0, stream>>>(x_scalar, x_sph, batch, b1, b2, p0, p1, p2,
                                         ws, out, N);
}

// Round 16
// 121.003 us; speedup vs baseline: 1.0741x; 1.0741x over previous
//
#include <hip/hip_runtime.h>
#include <math.h>

// ---------------------------------------------------------------------------
// MegaCartTensorOut, R16: R15 fused kernel + LDS aliasing for occupancy.
// R15 counters: fused worked (traffic 120->62MB, VGPR 52 clean) but occupancy
// fell to 38.6% (LDS 39.9KB -> 4 blocks/CU) and dur rose to 127us (> R14's
// 112). Fix: TW (phase-B write, phase-C read) aliases the dead P1+P2 staging
// region after the phase-A barrier. LDS 39936 -> 30720 -> 5 blocks/CU.
// ---------------------------------------------------------------------------

#define N_CG_FLOATS 438

typedef short s16x8 __attribute__((ext_vector_type(8)));
typedef short s16x4 __attribute__((ext_vector_type(4)));
typedef float f32x4 __attribute__((ext_vector_type(4)));

// pk region (units: shorts, from byte 2048 of ws) — ends at byte 69632
#define PK_BYTE_OFF 2048
#define PK_A1 0       // 16 frags (K=128,N=64)
#define PK_W0 8192    // 8  frags (K=128,N=32), *1/sqrt(128)
#define PK_A2 12288   // 36 frags (K=64, N=288)
#define PK_W1 30720   // 4  frags (K=64, N=32), *0.125
#define PK_W2 32768   // 2  frags (K=32, N=32), *1/sqrt(32)
#define PK_TOTAL 33792

__device__ __forceinline__ short f2bf(float f) {
  union { float f; unsigned u; } x; x.f = f;
  unsigned r = (x.u + 0x7FFFu + ((x.u >> 16) & 1u)) >> 16;
  return (short)r;
}
__device__ __forceinline__ float bf2f(unsigned short s) {
  union { unsigned u; float f; } x; x.u = ((unsigned)s) << 16;
  return x.f;
}

// ---------------- CG setup (verified rounds 1-15) ----------------------------

__device__ __forceinline__ double dfact(int n) {
  double r = 1.0;
  for (int i = 2; i <= n; ++i) r *= (double)i;
  return r;
}

__device__ __forceinline__ void u_elem(int l, int i, int j, double& re, double& im) {
  re = 0.0; im = 0.0;
  const int mr = i - l, mc = j - l;
  const double is2 = 0.70710678118654752440;
  if (mr == 0) { if (mc == 0) re = 1.0; }
  else if (mr > 0) {
    if (mc == mr) re = ((mr & 1) ? -1.0 : 1.0) * is2;
    else if (mc == -mr) re = is2;
  } else {
    int m = -mr;
    if (mc == m) im = -(((m & 1) ? -1.0 : 1.0)) * is2;
    else if (mc == -m) im = is2;
  }
}

__global__ void setup_cg_par(float* __restrict__ ws) {
  const int LAs[12] = {0, 1, 2, 1, 2, 0, 2, 1, 2, 1, 1, 1};
  const int LBs[12] = {0, 1, 2, 1, 2, 2, 0, 1, 2, 1, 1, 1};
  const int LOs[12] = {0, 0, 0, 1, 1, 2, 2, 2, 2, 0, 1, 2};
  const int OFF[12] = {0, 1, 10, 35, 62, 137, 162, 187, 232, 357, 366, 393};

  const int blk = blockIdx.x;
  const int l1 = LAs[blk], l2 = LBs[blk], l3 = LOs[blk];
  const double scale = (blk >= 9) ? sqrt(2.0 * l3 + 1.0) : 1.0;
  const int n1 = 2 * l1 + 1, n2 = 2 * l2 + 1, n3 = 2 * l3 + 1;
  const int nel = n1 * n2 * n3;
  const int t = threadIdx.x;

  __shared__ double Cs[125];
  __shared__ double Rre[125], Rim[125];
  __shared__ double s_inv;
  __shared__ int s_useRe;

  if (t < nel) {
    const int i3 = t % n3, i2 = (t / n3) % n2, i1 = t / (n3 * n2);
    const int m1 = i1 - l1, m2 = i2 - l2, m3 = i3 - l3;
    double val = 0.0;
    if (m1 + m2 == m3) {
      double pre = sqrt((2.0 * l3 + 1.0) * dfact(l1 + l2 - l3) * dfact(l1 - l2 + l3) *
                        dfact(-l1 + l2 + l3) / dfact(l1 + l2 + l3 + 1));
      pre *= sqrt(dfact(l3 + m3) * dfact(l3 - m3) * dfact(l1 - m1) * dfact(l1 + m1) *
                  dfact(l2 - m2) * dfact(l2 + m2));
      double s = 0.0;
      for (int k = 0; k <= l1 + l2 - l3; ++k) {
        int d1 = l1 + l2 - l3 - k, d2 = l1 - m1 - k, d3 = l2 + m2 - k;
        int d4 = l3 - l2 + m1 + k, d5 = l3 - l1 - m2 + k;
        if (d1 < 0 || d2 < 0 || d3 < 0 || d4 < 0 || d5 < 0) continue;
        double prod = dfact(k) * dfact(d1) * dfact(d2) * dfact(d3) * dfact(d4) * dfact(d5);
        s += ((k & 1) ? -1.0 : 1.0) / prod;
      }
      val = pre * s;
    }
    Cs[t] = val;
  }
  __syncthreads();

  if (t < nel) {
    const int c = t % n3, bb = (t / n3) % n2, a = t / (n3 * n2);
    double sr_ = 0.0, si_ = 0.0;
    for (int m = 0; m < n1; ++m) {
      double u1r, u1i;
      u_elem(l1, a, m, u1r, u1i);
      if (u1r == 0.0 && u1i == 0.0) continue;
      for (int nn = 0; nn < n2; ++nn) {
        double u2r, u2i;
        u_elem(l2, bb, nn, u2r, u2i);
        double t12r = u1r * u2r - u1i * u2i;
        double t12i = u1r * u2i + u1i * u2r;
        if (t12r == 0.0 && t12i == 0.0) continue;
        for (int o = 0; o < n3; ++o) {
          double cgv = Cs[(m * n2 + nn) * n3 + o];
          if (cgv == 0.0) continue;
          double u3r, u3i;
          u_elem(l3, c, o, u3r, u3i);
          sr_ += (t12r * u3r + t12i * u3i) * cgv;
          si_ += (t12i * u3r - t12r * u3i) * cgv;
        }
      }
    }
    Rre[t] = sr_;
    Rim[t] = si_;
  }
  __syncthreads();

  if (t == 0) {
    double maxRe = 0.0, maxIm = 0.0;
    for (int e = 0; e < nel; ++e) {
      maxRe = fmax(maxRe, fabs(Rre[e]));
      maxIm = fmax(maxIm, fabs(Rim[e]));
    }
    int useRe = (maxRe >= maxIm) ? 1 : 0;
    double nrm = 0.0;
    for (int e = 0; e < nel; ++e) {
      double vv = useRe ? Rre[e] : Rim[e];
      nrm += vv * vv;
    }
    s_useRe = useRe;
    s_inv = scale / sqrt(nrm);
  }
  __syncthreads();

  if (t < nel) {
    double vv = s_useRe ? Rre[t] : Rim[t];
    ws[OFF[blk] + t] = (float)(vv * s_inv);
  }
}

// ---------------- weight fragment packing ------------------------------------
__global__ void pack_weights(const float* __restrict__ A1, const float* __restrict__ W0,
                             const float* __restrict__ A2, const float* __restrict__ W1,
                             const float* __restrict__ W2, float* __restrict__ ws) {
  unsigned short* pk = (unsigned short*)((char*)ws + PK_BYTE_OFF);
  int e = blockIdx.x * 256 + threadIdx.x;
  if (e >= PK_TOTAL) return;
  const float* src;
  int Ncols, off;
  float scale;
  if (e < PK_W0)      { src = A1; Ncols = 64;  off = PK_A1; scale = 1.f; }
  else if (e < PK_A2) { src = W0; Ncols = 32;  off = PK_W0; scale = 0.08838834764831845f; }
  else if (e < PK_W1) { src = A2; Ncols = 288; off = PK_A2; scale = 1.f; }
  else if (e < PK_W2) { src = W1; Ncols = 32;  off = PK_W1; scale = 0.125f; }
  else                { src = W2; Ncols = 32;  off = PK_W2; scale = 0.17677669529663687f; }
  int local = e - off;
  int frag = local >> 9;
  int l = (local >> 3) & 63;
  int j = local & 7;
  int ntn = Ncols >> 4;
  int kt = frag / ntn, nt = frag - kt * ntn;
  int k = kt * 32 + 8 * (l >> 4) + j;
  int c = nt * 16 + (l & 15);
  pk[e] = (unsigned short)f2bf(src[k * Ncols + c] * scale);
}

// ---------------- shared helpers ---------------------------------------------

__device__ __forceinline__ s16x8 cvt8(const float* __restrict__ g) {
  float4 a = *(const float4*)g;
  float4 b = *(const float4*)(g + 4);
  s16x8 r;
  r[0] = f2bf(a.x); r[1] = f2bf(a.y); r[2] = f2bf(a.z); r[3] = f2bf(a.w);
  r[4] = f2bf(b.x); r[5] = f2bf(b.y); r[6] = f2bf(b.z); r[7] = f2bf(b.w);
  return r;
}

__device__ __forceinline__ void sw_wr8(char* sm, int base, int strideB, int r, int c0, s16x8 v) {
  int byte = base + r * strideB + c0 * 2;
  byte ^= (r & 7) << 4;
  *(s16x8*)(sm + byte) = v;
}
__device__ __forceinline__ s16x8 sw_lda16(const char* sm, int base, int strideB, int k0,
                                          int lane) {
  int r = lane & 15;
  int byte = base + r * strideB + (k0 + 8 * (lane >> 4)) * 2;
  byte ^= (r & 7) << 4;
  return *(const s16x8*)(sm + byte);
}

template <int LA, int LB, int LO>
__device__ __forceinline__ void tp_accum(const float* __restrict__ R, float w,
                                         const float* xa, const float* xb, float* sph) {
  constexpr int NA = 2 * LA + 1, NB = 2 * LB + 1, NC = 2 * LO + 1;
#pragma unroll
  for (int a = 0; a < NA; ++a) {
#pragma unroll
    for (int b = 0; b < NB; ++b) {
      float xab = xa[a] * xb[b] * w;
#pragma unroll
      for (int c = 0; c < NC; ++c) sph[c] = fmaf(xab, R[(a * NB + b) * NC + c], sph[c]);
    }
  }
}

// ================== fused main kernel ========================================
// LDS layout (bytes), 30720 total (5 blocks/CU):
//   XS 0..4096, SP 4096..8192, H 8192..10240 (all live through phase A/B)
//   P1 10240..16384, P2 16384..21504 (staging; DEAD after phase-A barrier)
//   TW 10240..19456  (phase-B write, phase-C read — aliases P1/P2, safe)
//   YA 21504..30720  (phase-A write, phase-C read)
#define F_XS 0
#define F_SP 4096
#define F_H  8192
#define F_P1 10240
#define F_P2 16384
#define F_TW 10240   // alias over P1/P2 after phase-A barrier
#define F_YA 21504
#define F_SMEM 30720

__global__ __launch_bounds__(256) void mega_fused(
    const float* __restrict__ xs_g, const float* __restrict__ sp_g,
    const int* __restrict__ batch, const float* __restrict__ b1,
    const float* __restrict__ b2, const float* __restrict__ p0,
    const float* __restrict__ p1, const float* __restrict__ p2,
    const float* __restrict__ ws, float* __restrict__ out, int N) {
  __shared__ char sm[F_SMEM];
  const unsigned short* pk = (const unsigned short*)((const char*)ws + PK_BYTE_OFF);
  const float* cg = ws;  // uniform base -> s_load (R13-proven anti-hoist)

  const int t = threadIdx.x;
  const int b0 = blockIdx.x * 16;
  const int lane = t & 63;
  const int wid = t >> 6;

  // ---- staging: xs + sp0 (b128 swz writes)
  {
    int n = t >> 4, c0 = (t & 15) * 8;
    long nn = min((long)(b0 + n), (long)N - 1);
    sw_wr8(sm, F_XS, 256, n, c0, cvt8(xs_g + nn * 128 + c0));
    sw_wr8(sm, F_SP, 256, n, c0, cvt8(sp_g + nn * 480 + c0));
  }
  // ---- staging: l1 planes (4 u's per thread)
  {
    int n = t >> 4, uc = t & 15;
    long nn = min((long)(b0 + n), (long)N - 1);
    const float* g = sp_g + nn * 480 + 128 + uc * 12;
    float4 a0 = *(const float4*)(g), a1 = *(const float4*)(g + 4), a2 = *(const float4*)(g + 8);
    float fl[12] = {a0.x, a0.y, a0.z, a0.w, a1.x, a1.y, a1.z, a1.w, a2.x, a2.y, a2.z, a2.w};
#pragma unroll
    for (int m = 0; m < 3; ++m) {
      s16x4 e;
#pragma unroll
      for (int j = 0; j < 4; ++j) e[j] = f2bf(fl[j * 3 + m]);
      int byte = F_P1 + m * 2048 + n * 128 + uc * 8;
      byte ^= (n & 7) << 4;
      *(s16x4*)(sm + byte) = e;
    }
  }
  // ---- staging: l2 planes (threads < 128, 4 u's per thread)
  if (t < 128) {
    int n = t >> 3, uc = t & 7;
    long nn = min((long)(b0 + n), (long)N - 1);
    const float* g = sp_g + nn * 480 + 320 + uc * 20;
    float4 a0 = *(const float4*)(g), a1 = *(const float4*)(g + 4), a2 = *(const float4*)(g + 8),
           a3 = *(const float4*)(g + 12), a4 = *(const float4*)(g + 16);
    float fl[20] = {a0.x, a0.y, a0.z, a0.w, a1.x, a1.y, a1.z, a1.w, a2.x, a2.y,
                    a2.z, a2.w, a3.x, a3.y, a3.z, a3.w, a4.x, a4.y, a4.z, a4.w};
#pragma unroll
    for (int m = 0; m < 5; ++m) {
      s16x4 e;
#pragma unroll
      for (int j = 0; j < 4; ++j) e[j] = f2bf(fl[j * 5 + m]);
      int byte = F_P2 + m * 1024 + n * 64 + uc * 8;
      byte ^= (n & 7) << 4;
      *(s16x4*)(sm + byte) = e;
    }
  }
  __syncthreads();

  // ---- phase A: h GEMM + y0/y1/y2 tiles -> LDS (P1/P2 last read here)
  {
    f32x4 acc = {0.f, 0.f, 0.f, 0.f};
#pragma unroll
    for (int kt = 0; kt < 4; ++kt) {
      s16x8 a = sw_lda16(sm, F_XS, 256, kt * 32, lane);
      s16x8 b = *(const s16x8*)(pk + PK_A1 + (((kt << 2) + wid) * 64 + lane) * 8);
      acc = __builtin_amdgcn_mfma_f32_16x16x32_bf16(a, b, acc, 0, 0, 0);
    }
    const int col = wid * 16 + (lane & 15);
    const int r0 = (lane >> 4) * 4;
    const float bb = b1[col];
#pragma unroll
    for (int q = 0; q < 4; ++q) {
      float hv = acc[q] + bb;
      hv = hv / (1.f + __expf(-hv));
      int r = r0 + q;
      int byte = F_H + r * 128 + col * 2;
      byte ^= (r & 7) << 4;
      *(short*)(sm + byte) = f2bf(hv);
    }
  }

  const int r0 = (lane >> 4) * 4;
  if (wid < 2) {  // y0 -> YA cols 0..31
    f32x4 acc = {0.f, 0.f, 0.f, 0.f};
#pragma unroll
    for (int kt = 0; kt < 4; ++kt) {
      s16x8 a = sw_lda16(sm, F_SP, 256, kt * 32, lane);
      s16x8 b = *(const s16x8*)(pk + PK_W0 + (((kt << 1) + wid) * 64 + lane) * 8);
      acc = __builtin_amdgcn_mfma_f32_16x16x32_bf16(a, b, acc, 0, 0, 0);
    }
    const int col = wid * 16 + (lane & 15);
#pragma unroll
    for (int q = 0; q < 4; ++q)
      *(short*)(sm + F_YA + (r0 + q) * 576 + col * 2) = f2bf(acc[q]);
  }
  for (int tl = wid; tl < 6; tl += 4) {  // y1 -> YA cols 32..127
    const int m = tl >> 1, nt = tl & 1;
    f32x4 acc = {0.f, 0.f, 0.f, 0.f};
#pragma unroll
    for (int kt = 0; kt < 2; ++kt) {
      s16x8 a = sw_lda16(sm, F_P1 + m * 2048, 128, kt * 32, lane);
      s16x8 b = *(const s16x8*)(pk + PK_W1 + (((kt << 1) + nt) * 64 + lane) * 8);
      acc = __builtin_amdgcn_mfma_f32_16x16x32_bf16(a, b, acc, 0, 0, 0);
    }
    const int col = 32 + m * 32 + nt * 16 + (lane & 15);
#pragma unroll
    for (int q = 0; q < 4; ++q)
      *(short*)(sm + F_YA + (r0 + q) * 576 + col * 2) = f2bf(acc[q]);
  }
  for (int tl = wid; tl < 10; tl += 4) {  // y2 -> YA cols 128..287
    const int m = tl >> 1, nt = tl & 1;
    f32x4 acc = {0.f, 0.f, 0.f, 0.f};
    {
      s16x8 a = sw_lda16(sm, F_P2 + m * 1024, 64, 0, lane);
      s16x8 b = *(const s16x8*)(pk + PK_W2 + (nt * 64 + lane) * 8);
      acc = __builtin_amdgcn_mfma_f32_16x16x32_bf16(a, b, acc, 0, 0, 0);
    }
    const int col = 128 + m * 32 + nt * 16 + (lane & 15);
#pragma unroll
    for (int q = 0; q < 4; ++q)
      *(short*)(sm + F_YA + (r0 + q) * 576 + col * 2) = f2bf(acc[q]);
  }
  __syncthreads();  // H + YA ready; P1/P2 now dead -> TW may alias

  // ---- phase B: tw = h @ A2 + b2 -> TW LDS (aliases P1/P2)
  for (int tl = wid; tl < 18; tl += 4) {
    f32x4 acc = {0.f, 0.f, 0.f, 0.f};
#pragma unroll
    for (int kt = 0; kt < 2; ++kt) {
      s16x8 a = sw_lda16(sm, F_H, 128, kt * 32, lane);
      s16x8 b = *(const s16x8*)(pk + PK_A2 + ((kt * 18 + tl) * 64 + lane) * 8);
      acc = __builtin_amdgcn_mfma_f32_16x16x32_bf16(a, b, acc, 0, 0, 0);
    }
    const int col = tl * 16 + (lane & 15);
    const float bb = b2[col];
#pragma unroll
    for (int q = 0; q < 4; ++q)
      *(short*)(sm + F_TW + (r0 + q) * 576 + col * 2) = f2bf(acc[q] + bb);
  }
  __syncthreads();

  // ---- phase C: RMS + TP + cart + segment-sum (CG via SGPR global loads)
  const int v = t & 31;
  const int sl = t >> 5;
  const float invs32 = 0.17677669529663687f;
  const float k0c = invs32 / 3.0f;
  const float k1c = 1.7320508075688772f * invs32 / 2.0f;
  const float k2c = 2.23606797749979f * invs32 / 4.0f;
  const float c0 = k0c * p0[0], c1 = k0c * p0[1], c2 = k0c * p0[2];
  const float c3 = k1c * p1[0], c4 = k1c * p1[1];
  const float c5 = k2c * p2[0], c6 = k2c * p2[1], c7 = k2c * p2[2], c8 = k2c * p2[3];
  const float* qb0 = cg + 357;
  const float* qb1 = cg + 366;
  const float* qb2 = cg + 393;

#pragma unroll 1
  for (int r = 0; r < 2; ++r) {
    const int nrow = sl + 8 * r;
    const int n = b0 + nrow;
    const unsigned short* yb = (const unsigned short*)(sm + F_YA + nrow * 576);
    const unsigned short* tb = (const unsigned short*)(sm + F_TW + nrow * 576);

    const float y0v = bf2f(yb[v]);
    float y1[3], y2[5];
#pragma unroll
    for (int m = 0; m < 3; ++m) y1[m] = bf2f(yb[32 + m * 32 + v]);
#pragma unroll
    for (int m = 0; m < 5; ++m) y2[m] = bf2f(yb[128 + m * 32 + v]);

    float s0 = y0v * y0v;
    float s1 = y1[0] * y1[0] + y1[1] * y1[1] + y1[2] * y1[2];
    float s2 = 0.f;
#pragma unroll
    for (int m = 0; m < 5; ++m) s2 = fmaf(y2[m], y2[m], s2);
#pragma unroll
    for (int msk = 16; msk >= 1; msk >>= 1) {
      s0 += __shfl_xor(s0, msk);
      s1 += __shfl_xor(s1, msk);
      s2 += __shfl_xor(s2, msk);
    }
    const float i0 = 1.0f / sqrtf(s0 * (1.0f / 32.0f) + 1e-5f);
    const float i1 = 1.0f / sqrtf(s1 * (1.0f / 96.0f) + 1e-5f);
    const float i2 = 1.0f / sqrtf(s2 * (1.0f / 160.0f) + 1e-5f);
    float xs0[1] = {y0v * i0};
    float xs1[3], xs2[5];
#pragma unroll
    for (int m = 0; m < 3; ++m) xs1[m] = y1[m] * i1;
#pragma unroll
    for (int m = 0; m < 5; ++m) xs2[m] = y2[m] * i2;

    float w9[9];
#pragma unroll
    for (int i = 0; i < 9; ++i) w9[i] = bf2f(tb[i * 32 + v]);

    float sph0[1] = {0.f};
    float sph1[3] = {0.f, 0.f, 0.f};
    float sph2[5] = {0.f, 0.f, 0.f, 0.f, 0.f};
    tp_accum<0, 0, 0>(cg + 0,   w9[0] * c0, xs0, xs0, sph0);
    tp_accum<1, 1, 0>(cg + 1,   w9[1] * c1, xs1, xs1, sph0);
    tp_accum<2, 2, 0>(cg + 10,  w9[2] * c2, xs2, xs2, sph0);
    tp_accum<1, 1, 1>(cg + 35,  w9[3] * c3, xs1, xs1, sph1);
    tp_accum<2, 2, 1>(cg + 62,  w9[4] * c4, xs2, xs2, sph1);
    tp_accum<0, 2, 2>(cg + 137, w9[5] * c5, xs0, xs2, sph2);
    tp_accum<2, 0, 2>(cg + 162, w9[6] * c6, xs2, xs0, sph2);
    tp_accum<1, 1, 2>(cg + 187, w9[7] * c7, xs1, xs1, sph2);
    tp_accum<2, 2, 2>(cg + 232, w9[8] * c8, xs2, xs2, sph2);

#pragma unroll
    for (int msk = 16; msk >= 1; msk >>= 1) {
      sph0[0] += __shfl_xor(sph0[0], msk);
#pragma unroll
      for (int m = 0; m < 3; ++m) sph1[m] += __shfl_xor(sph1[m], msk);
#pragma unroll
      for (int m = 0; m < 5; ++m) sph2[m] += __shfl_xor(sph2[m], msk);
    }

    // cart: lanes 0..8 each compute one (i,j) — sums live in ALL lanes
    if (v < 9 && n < N) {
      const int i = v / 3, j = v - 3 * i;
      float val = sph0[0] * qb0[v];
#pragma unroll
      for (int m = 0; m < 3; ++m) val = fmaf(sph1[m], qb1[v * 3 + m], val);
#pragma unroll
      for (int m = 0; m < 5; ++m) val = fmaf(sph2[m], qb2[v * 5 + m], val);
      float* og = out + (long)batch[n] * 9;
      atomicAdd(&og[((i + 1) % 3) * 3 + ((j + 1) % 3)], val);
    }
  }
}

// ---------------------------------------------------------------------------

extern "C" void kernel_launch(void* const* d_in, const int* in_sizes, int n_in,
                              void* d_out, int out_size, void* d_ws, size_t ws_size,
                              hipStream_t stream) {
  const float* x_scalar = (const float*)d_in[0];
  const float* x_sph    = (const float*)d_in[1];
  const int*   batch    = (const int*)d_in[2];
  const float* W0 = (const float*)d_in[4];
  const float* W1 = (const float*)d_in[5];
  const float* W2 = (const float*)d_in[6];
  const float* A1 = (const float*)d_in[7];
  const float* b1 = (const float*)d_in[8];
  const float* A2 = (const float*)d_in[9];
  const float* b2 = (const float*)d_in[10];
  const float* p0 = (const float*)d_in[11];
  const float* p1 = (const float*)d_in[12];
  const float* p2 = (const float*)d_in[13];
  float* out = (float*)d_out;
  float* ws  = (float*)d_ws;

  const int N = in_sizes[0] / 128;

  hipMemsetAsync(d_out, 0, (size_t)out_size * sizeof(float), stream);
  setup_cg_par<<<12, 128, 0, stream>>>(ws);
  pack_weights<<<(PK_TOTAL + 255) / 256, 256, 0, stream>>>(A1, W0, A2, W1, W2, ws);
  const int blocks = (N + 15) / 16;
  mega_fused<<<blocks, 256, 0, stream>>>(x_scalar, x_sph, batch, b1, b2, p0, p1, p2,
                                         ws, out, N);
}

// Round 17
// 107.519 us; speedup vs baseline: 1.2088x; 1.1254x over previous
//
#include <hip/hip_runtime.h>
#include <math.h>

// ---------------------------------------------------------------------------
// MegaCartTensorOut, R17: fused kernel at 512 threads/block.
// R16 counters: VALUBusy 48% ~= occupancy 48% -> wave-count-limited.
// 256t x 5 blocks/CU = 20 waves (62.5%). 512t blocks: 4 blocks/CU (thread
// limit) x 8 waves = 32 waves = 100% ceiling; phase C single-pass (16 slots);
// staging halves per thread. VGPR must stay <=64 (current 44 fits).
// Numerics/swizzles/SGPR-CG/aliasing identical to passing R16.
// ---------------------------------------------------------------------------

#define N_CG_FLOATS 438

typedef short s16x8 __attribute__((ext_vector_type(8)));
typedef short s16x4 __attribute__((ext_vector_type(4)));
typedef float f32x4 __attribute__((ext_vector_type(4)));

// pk region (units: shorts, from byte 2048 of ws) — ends at byte 69632
#define PK_BYTE_OFF 2048
#define PK_A1 0       // 16 frags (K=128,N=64)
#define PK_W0 8192    // 8  frags (K=128,N=32), *1/sqrt(128)
#define PK_A2 12288   // 36 frags (K=64, N=288)
#define PK_W1 30720   // 4  frags (K=64, N=32), *0.125
#define PK_W2 32768   // 2  frags (K=32, N=32), *1/sqrt(32)
#define PK_TOTAL 33792

__device__ __forceinline__ short f2bf(float f) {
  union { float f; unsigned u; } x; x.f = f;
  unsigned r = (x.u + 0x7FFFu + ((x.u >> 16) & 1u)) >> 16;
  return (short)r;
}
__device__ __forceinline__ float bf2f(unsigned short s) {
  union { unsigned u; float f; } x; x.u = ((unsigned)s) << 16;
  return x.f;
}

// ---------------- CG setup (verified rounds 1-16) ----------------------------

__device__ __forceinline__ double dfact(int n) {
  double r = 1.0;
  for (int i = 2; i <= n; ++i) r *= (double)i;
  return r;
}

__device__ __forceinline__ void u_elem(int l, int i, int j, double& re, double& im) {
  re = 0.0; im = 0.0;
  const int mr = i - l, mc = j - l;
  const double is2 = 0.70710678118654752440;
  if (mr == 0) { if (mc == 0) re = 1.0; }
  else if (mr > 0) {
    if (mc == mr) re = ((mr & 1) ? -1.0 : 1.0) * is2;
    else if (mc == -mr) re = is2;
  } else {
    int m = -mr;
    if (mc == m) im = -(((m & 1) ? -1.0 : 1.0)) * is2;
    else if (mc == -m) im = is2;
  }
}

__global__ void setup_cg_par(float* __restrict__ ws) {
  const int LAs[12] = {0, 1, 2, 1, 2, 0, 2, 1, 2, 1, 1, 1};
  const int LBs[12] = {0, 1, 2, 1, 2, 2, 0, 1, 2, 1, 1, 1};
  const int LOs[12] = {0, 0, 0, 1, 1, 2, 2, 2, 2, 0, 1, 2};
  const int OFF[12] = {0, 1, 10, 35, 62, 137, 162, 187, 232, 357, 366, 393};

  const int blk = blockIdx.x;
  const int l1 = LAs[blk], l2 = LBs[blk], l3 = LOs[blk];
  const double scale = (blk >= 9) ? sqrt(2.0 * l3 + 1.0) : 1.0;
  const int n1 = 2 * l1 + 1, n2 = 2 * l2 + 1, n3 = 2 * l3 + 1;
  const int nel = n1 * n2 * n3;
  const int t = threadIdx.x;

  __shared__ double Cs[125];
  __shared__ double Rre[125], Rim[125];
  __shared__ double s_inv;
  __shared__ int s_useRe;

  if (t < nel) {
    const int i3 = t % n3, i2 = (t / n3) % n2, i1 = t / (n3 * n2);
    const int m1 = i1 - l1, m2 = i2 - l2, m3 = i3 - l3;
    double val = 0.0;
    if (m1 + m2 == m3) {
      double pre = sqrt((2.0 * l3 + 1.0) * dfact(l1 + l2 - l3) * dfact(l1 - l2 + l3) *
                        dfact(-l1 + l2 + l3) / dfact(l1 + l2 + l3 + 1));
      pre *= sqrt(dfact(l3 + m3) * dfact(l3 - m3) * dfact(l1 - m1) * dfact(l1 + m1) *
                  dfact(l2 - m2) * dfact(l2 + m2));
      double s = 0.0;
      for (int k = 0; k <= l1 + l2 - l3; ++k) {
        int d1 = l1 + l2 - l3 - k, d2 = l1 - m1 - k, d3 = l2 + m2 - k;
        int d4 = l3 - l2 + m1 + k, d5 = l3 - l1 - m2 + k;
        if (d1 < 0 || d2 < 0 || d3 < 0 || d4 < 0 || d5 < 0) continue;
        double prod = dfact(k) * dfact(d1) * dfact(d2) * dfact(d3) * dfact(d4) * dfact(d5);
        s += ((k & 1) ? -1.0 : 1.0) / prod;
      }
      val = pre * s;
    }
    Cs[t] = val;
  }
  __syncthreads();

  if (t < nel) {
    const int c = t % n3, bb = (t / n3) % n2, a = t / (n3 * n2);
    double sr_ = 0.0, si_ = 0.0;
    for (int m = 0; m < n1; ++m) {
      double u1r, u1i;
      u_elem(l1, a, m, u1r, u1i);
      if (u1r == 0.0 && u1i == 0.0) continue;
      for (int nn = 0; nn < n2; ++nn) {
        double u2r, u2i;
        u_elem(l2, bb, nn, u2r, u2i);
        double t12r = u1r * u2r - u1i * u2i;
        double t12i = u1r * u2i + u1i * u2r;
        if (t12r == 0.0 && t12i == 0.0) continue;
        for (int o = 0; o < n3; ++o) {
          double cgv = Cs[(m * n2 + nn) * n3 + o];
          if (cgv == 0.0) continue;
          double u3r, u3i;
          u_elem(l3, c, o, u3r, u3i);
          sr_ += (t12r * u3r + t12i * u3i) * cgv;
          si_ += (t12i * u3r - t12r * u3i) * cgv;
        }
      }
    }
    Rre[t] = sr_;
    Rim[t] = si_;
  }
  __syncthreads();

  if (t == 0) {
    double maxRe = 0.0, maxIm = 0.0;
    for (int e = 0; e < nel; ++e) {
      maxRe = fmax(maxRe, fabs(Rre[e]));
      maxIm = fmax(maxIm, fabs(Rim[e]));
    }
    int useRe = (maxRe >= maxIm) ? 1 : 0;
    double nrm = 0.0;
    for (int e = 0; e < nel; ++e) {
      double vv = useRe ? Rre[e] : Rim[e];
      nrm += vv * vv;
    }
    s_useRe = useRe;
    s_inv = scale / sqrt(nrm);
  }
  __syncthreads();

  if (t < nel) {
    double vv = s_useRe ? Rre[t] : Rim[t];
    ws[OFF[blk] + t] = (float)(vv * s_inv);
  }
}

// ---------------- weight fragment packing ------------------------------------
__global__ void pack_weights(const float* __restrict__ A1, const float* __restrict__ W0,
                             const float* __restrict__ A2, const float* __restrict__ W1,
                             const float* __restrict__ W2, float* __restrict__ ws) {
  unsigned short* pk = (unsigned short*)((char*)ws + PK_BYTE_OFF);
  int e = blockIdx.x * 256 + threadIdx.x;
  if (e >= PK_TOTAL) return;
  const float* src;
  int Ncols, off;
  float scale;
  if (e < PK_W0)      { src = A1; Ncols = 64;  off = PK_A1; scale = 1.f; }
  else if (e < PK_A2) { src = W0; Ncols = 32;  off = PK_W0; scale = 0.08838834764831845f; }
  else if (e < PK_W1) { src = A2; Ncols = 288; off = PK_A2; scale = 1.f; }
  else if (e < PK_W2) { src = W1; Ncols = 32;  off = PK_W1; scale = 0.125f; }
  else                { src = W2; Ncols = 32;  off = PK_W2; scale = 0.17677669529663687f; }
  int local = e - off;
  int frag = local >> 9;
  int l = (local >> 3) & 63;
  int j = local & 7;
  int ntn = Ncols >> 4;
  int kt = frag / ntn, nt = frag - kt * ntn;
  int k = kt * 32 + 8 * (l >> 4) + j;
  int c = nt * 16 + (l & 15);
  pk[e] = (unsigned short)f2bf(src[k * Ncols + c] * scale);
}

// ---------------- shared helpers ---------------------------------------------

__device__ __forceinline__ s16x8 cvt8(const float* __restrict__ g) {
  float4 a = *(const float4*)g;
  float4 b = *(const float4*)(g + 4);
  s16x8 r;
  r[0] = f2bf(a.x); r[1] = f2bf(a.y); r[2] = f2bf(a.z); r[3] = f2bf(a.w);
  r[4] = f2bf(b.x); r[5] = f2bf(b.y); r[6] = f2bf(b.z); r[7] = f2bf(b.w);
  return r;
}

__device__ __forceinline__ void sw_wr8(char* sm, int base, int strideB, int r, int c0, s16x8 v) {
  int byte = base + r * strideB + c0 * 2;
  byte ^= (r & 7) << 4;
  *(s16x8*)(sm + byte) = v;
}
__device__ __forceinline__ s16x8 sw_lda16(const char* sm, int base, int strideB, int k0,
                                          int lane) {
  int r = lane & 15;
  int byte = base + r * strideB + (k0 + 8 * (lane >> 4)) * 2;
  byte ^= (r & 7) << 4;
  return *(const s16x8*)(sm + byte);
}

template <int LA, int LB, int LO>
__device__ __forceinline__ void tp_accum(const float* __restrict__ R, float w,
                                         const float* xa, const float* xb, float* sph) {
  constexpr int NA = 2 * LA + 1, NB = 2 * LB + 1, NC = 2 * LO + 1;
#pragma unroll
  for (int a = 0; a < NA; ++a) {
#pragma unroll
    for (int b = 0; b < NB; ++b) {
      float xab = xa[a] * xb[b] * w;
#pragma unroll
      for (int c = 0; c < NC; ++c) sph[c] = fmaf(xab, R[(a * NB + b) * NC + c], sph[c]);
    }
  }
}

// ================== fused main kernel (512 threads) ==========================
// LDS layout (bytes), 30720 total:
//   XS 0..4096, SP 4096..8192, H 8192..10240
//   P1 10240..16384, P2 16384..21504 (staging; dead after phase-A barrier)
//   TW 10240..19456 (aliases P1/P2 after phase-A barrier)
//   YA 21504..30720
#define F_XS 0
#define F_SP 4096
#define F_H  8192
#define F_P1 10240
#define F_P2 16384
#define F_TW 10240
#define F_YA 21504
#define F_SMEM 30720

__global__ __launch_bounds__(512) void mega_fused(
    const float* __restrict__ xs_g, const float* __restrict__ sp_g,
    const int* __restrict__ batch, const float* __restrict__ b1,
    const float* __restrict__ b2, const float* __restrict__ p0,
    const float* __restrict__ p1, const float* __restrict__ p2,
    const float* __restrict__ ws, float* __restrict__ out, int N) {
  __shared__ char sm[F_SMEM];
  const unsigned short* pk = (const unsigned short*)((const char*)ws + PK_BYTE_OFF);
  const float* cg = ws;  // uniform base -> s_load (anti-hoist, R13-proven)

  const int t = threadIdx.x;
  const int b0 = blockIdx.x * 16;
  const int lane = t & 63;
  const int wid = t >> 6;  // 0..7

  // ---- staging (512 threads)
  if (t < 256) {
    // xs chunks: 16 rows x 16 chunks
    int n = t >> 4, c0 = (t & 15) * 8;
    long nn = min((long)(b0 + n), (long)N - 1);
    sw_wr8(sm, F_XS, 256, n, c0, cvt8(xs_g + nn * 128 + c0));
    // l1 planes: 16 rows x 16 uc (4 u's each)
    const float* g = sp_g + nn * 480 + 128 + (t & 15) * 12;
    float4 a0 = *(const float4*)(g), a1 = *(const float4*)(g + 4), a2 = *(const float4*)(g + 8);
    float fl[12] = {a0.x, a0.y, a0.z, a0.w, a1.x, a1.y, a1.z, a1.w, a2.x, a2.y, a2.z, a2.w};
#pragma unroll
    for (int m = 0; m < 3; ++m) {
      s16x4 e;
#pragma unroll
      for (int j = 0; j < 4; ++j) e[j] = f2bf(fl[j * 3 + m]);
      int byte = F_P1 + m * 2048 + n * 128 + (t & 15) * 8;
      byte ^= (n & 7) << 4;
      *(s16x4*)(sm + byte) = e;
    }
  } else {
    // sp0 chunks: 16 rows x 16 chunks
    int u = t - 256;
    int n = u >> 4, c0 = (u & 15) * 8;
    long nn = min((long)(b0 + n), (long)N - 1);
    sw_wr8(sm, F_SP, 256, n, c0, cvt8(sp_g + nn * 480 + c0));
    // l2 planes: 16 rows x 8 uc (4 u's each) — threads 256..383
    if (u < 128) {
      int n2_ = u >> 3, uc = u & 7;
      long nn2 = min((long)(b0 + n2_), (long)N - 1);
      const float* g = sp_g + nn2 * 480 + 320 + uc * 20;
      float4 a0 = *(const float4*)(g), a1 = *(const float4*)(g + 4), a2 = *(const float4*)(g + 8),
             a3 = *(const float4*)(g + 12), a4 = *(const float4*)(g + 16);
      float fl[20] = {a0.x, a0.y, a0.z, a0.w, a1.x, a1.y, a1.z, a1.w, a2.x, a2.y,
                      a2.z, a2.w, a3.x, a3.y, a3.z, a3.w, a4.x, a4.y, a4.z, a4.w};
#pragma unroll
      for (int m = 0; m < 5; ++m) {
        s16x4 e;
#pragma unroll
        for (int j = 0; j < 4; ++j) e[j] = f2bf(fl[j * 5 + m]);
        int byte = F_P2 + m * 1024 + n2_ * 64 + uc * 8;
        byte ^= (n2_ & 7) << 4;
        *(s16x4*)(sm + byte) = e;
      }
    }
  }
  __syncthreads();

  // ---- phase A: h (4 tiles, wid 0-3) + y0 (2, wid 4-5) + y1 (6) + y2 (10)
  const int r0 = (lane >> 4) * 4;
  if (wid < 4) {  // h = silu(xs @ A1 + b1), nt = wid
    f32x4 acc = {0.f, 0.f, 0.f, 0.f};
#pragma unroll
    for (int kt = 0; kt < 4; ++kt) {
      s16x8 a = sw_lda16(sm, F_XS, 256, kt * 32, lane);
      s16x8 b = *(const s16x8*)(pk + PK_A1 + (((kt << 2) + wid) * 64 + lane) * 8);
      acc = __builtin_amdgcn_mfma_f32_16x16x32_bf16(a, b, acc, 0, 0, 0);
    }
    const int col = wid * 16 + (lane & 15);
    const float bb = b1[col];
#pragma unroll
    for (int q = 0; q < 4; ++q) {
      float hv = acc[q] + bb;
      hv = hv / (1.f + __expf(-hv));
      int r = r0 + q;
      int byte = F_H + r * 128 + col * 2;
      byte ^= (r & 7) << 4;
      *(short*)(sm + byte) = f2bf(hv);
    }
  } else if (wid < 6) {  // y0, nt = wid-4
    const int nt = wid - 4;
    f32x4 acc = {0.f, 0.f, 0.f, 0.f};
#pragma unroll
    for (int kt = 0; kt < 4; ++kt) {
      s16x8 a = sw_lda16(sm, F_SP, 256, kt * 32, lane);
      s16x8 b = *(const s16x8*)(pk + PK_W0 + (((kt << 1) + nt) * 64 + lane) * 8);
      acc = __builtin_amdgcn_mfma_f32_16x16x32_bf16(a, b, acc, 0, 0, 0);
    }
    const int col = nt * 16 + (lane & 15);
#pragma unroll
    for (int q = 0; q < 4; ++q)
      *(short*)(sm + F_YA + (r0 + q) * 576 + col * 2) = f2bf(acc[q]);
  }
  for (int tl = wid; tl < 6; tl += 8) {  // y1 -> YA cols 32..127
    const int m = tl >> 1, nt = tl & 1;
    f32x4 acc = {0.f, 0.f, 0.f, 0.f};
#pragma unroll
    for (int kt = 0; kt < 2; ++kt) {
      s16x8 a = sw_lda16(sm, F_P1 + m * 2048, 128, kt * 32, lane);
      s16x8 b = *(const s16x8*)(pk + PK_W1 + (((kt << 1) + nt) * 64 + lane) * 8);
      acc = __builtin_amdgcn_mfma_f32_16x16x32_bf16(a, b, acc, 0, 0, 0);
    }
    const int col = 32 + m * 32 + nt * 16 + (lane & 15);
#pragma unroll
    for (int q = 0; q < 4; ++q)
      *(short*)(sm + F_YA + (r0 + q) * 576 + col * 2) = f2bf(acc[q]);
  }
  for (int tl = wid; tl < 10; tl += 8) {  // y2 -> YA cols 128..287
    const int m = tl >> 1, nt = tl & 1;
    f32x4 acc = {0.f, 0.f, 0.f, 0.f};
    {
      s16x8 a = sw_lda16(sm, F_P2 + m * 1024, 64, 0, lane);
      s16x8 b = *(const s16x8*)(pk + PK_W2 + (nt * 64 + lane) * 8);
      acc = __builtin_amdgcn_mfma_f32_16x16x32_bf16(a, b, acc, 0, 0, 0);
    }
    const int col = 128 + m * 32 + nt * 16 + (lane & 15);
#pragma unroll
    for (int q = 0; q < 4; ++q)
      *(short*)(sm + F_YA + (r0 + q) * 576 + col * 2) = f2bf(acc[q]);
  }
  __syncthreads();  // H + YA ready; P1/P2 dead -> TW may alias

  // ---- phase B: tw = h @ A2 + b2 -> TW (18 tiles over 8 waves)
  for (int tl = wid; tl < 18; tl += 8) {
    f32x4 acc = {0.f, 0.f, 0.f, 0.f};
#pragma unroll
    for (int kt = 0; kt < 2; ++kt) {
      s16x8 a = sw_lda16(sm, F_H, 128, kt * 32, lane);
      s16x8 b = *(const s16x8*)(pk + PK_A2 + ((kt * 18 + tl) * 64 + lane) * 8);
      acc = __builtin_amdgcn_mfma_f32_16x16x32_bf16(a, b, acc, 0, 0, 0);
    }
    const int col = tl * 16 + (lane & 15);
    const float bb = b2[col];
#pragma unroll
    for (int q = 0; q < 4; ++q)
      *(short*)(sm + F_TW + (r0 + q) * 576 + col * 2) = f2bf(acc[q] + bb);
  }
  __syncthreads();

  // ---- phase C: single pass, 16 slots x 32 lanes
  const int v = t & 31;
  const int sl = t >> 5;  // 0..15
  const float invs32 = 0.17677669529663687f;
  const float k0c = invs32 / 3.0f;
  const float k1c = 1.7320508075688772f * invs32 / 2.0f;
  const float k2c = 2.23606797749979f * invs32 / 4.0f;
  const float c0 = k0c * p0[0], c1 = k0c * p0[1], c2 = k0c * p0[2];
  const float c3 = k1c * p1[0], c4 = k1c * p1[1];
  const float c5 = k2c * p2[0], c6 = k2c * p2[1], c7 = k2c * p2[2], c8 = k2c * p2[3];
  const float* qb0 = cg + 357;
  const float* qb1 = cg + 366;
  const float* qb2 = cg + 393;

  const int n = b0 + sl;
  const unsigned short* yb = (const unsigned short*)(sm + F_YA + sl * 576);
  const unsigned short* tb = (const unsigned short*)(sm + F_TW + sl * 576);

  const float y0v = bf2f(yb[v]);
  float y1[3], y2[5];
#pragma unroll
  for (int m = 0; m < 3; ++m) y1[m] = bf2f(yb[32 + m * 32 + v]);
#pragma unroll
  for (int m = 0; m < 5; ++m) y2[m] = bf2f(yb[128 + m * 32 + v]);

  float s0 = y0v * y0v;
  float s1 = y1[0] * y1[0] + y1[1] * y1[1] + y1[2] * y1[2];
  float s2 = 0.f;
#pragma unroll
  for (int m = 0; m < 5; ++m) s2 = fmaf(y2[m], y2[m], s2);
#pragma unroll
  for (int msk = 16; msk >= 1; msk >>= 1) {
    s0 += __shfl_xor(s0, msk);
    s1 += __shfl_xor(s1, msk);
    s2 += __shfl_xor(s2, msk);
  }
  const float i0 = 1.0f / sqrtf(s0 * (1.0f / 32.0f) + 1e-5f);
  const float i1 = 1.0f / sqrtf(s1 * (1.0f / 96.0f) + 1e-5f);
  const float i2 = 1.0f / sqrtf(s2 * (1.0f / 160.0f) + 1e-5f);
  float xs0[1] = {y0v * i0};
  float xs1[3], xs2[5];
#pragma unroll
  for (int m = 0; m < 3; ++m) xs1[m] = y1[m] * i1;
#pragma unroll
  for (int m = 0; m < 5; ++m) xs2[m] = y2[m] * i2;

  float w9[9];
#pragma unroll
  for (int i = 0; i < 9; ++i) w9[i] = bf2f(tb[i * 32 + v]);

  float sph0[1] = {0.f};
  float sph1[3] = {0.f, 0.f, 0.f};
  float sph2[5] = {0.f, 0.f, 0.f, 0.f, 0.f};
  tp_accum<0, 0, 0>(cg + 0,   w9[0] * c0, xs0, xs0, sph0);
  tp_accum<1, 1, 0>(cg + 1,   w9[1] * c1, xs1, xs1, sph0);
  tp_accum<2, 2, 0>(cg + 10,  w9[2] * c2, xs2, xs2, sph0);
  tp_accum<1, 1, 1>(cg + 35,  w9[3] * c3, xs1, xs1, sph1);
  tp_accum<2, 2, 1>(cg + 62,  w9[4] * c4, xs2, xs2, sph1);
  tp_accum<0, 2, 2>(cg + 137, w9[5] * c5, xs0, xs2, sph2);
  tp_accum<2, 0, 2>(cg + 162, w9[6] * c6, xs2, xs0, sph2);
  tp_accum<1, 1, 2>(cg + 187, w9[7] * c7, xs1, xs1, sph2);
  tp_accum<2, 2, 2>(cg + 232, w9[8] * c8, xs2, xs2, sph2);

#pragma unroll
  for (int msk = 16; msk >= 1; msk >>= 1) {
    sph0[0] += __shfl_xor(sph0[0], msk);
#pragma unroll
    for (int m = 0; m < 3; ++m) sph1[m] += __shfl_xor(sph1[m], msk);
#pragma unroll
    for (int m = 0; m < 5; ++m) sph2[m] += __shfl_xor(sph2[m], msk);
  }

  // cart: lanes 0..8 each compute one (i,j) — sums live in ALL lanes
  if (v < 9 && n < N) {
    const int i = v / 3, j = v - 3 * i;
    float val = sph0[0] * qb0[v];
#pragma unroll
    for (int m = 0; m < 3; ++m) val = fmaf(sph1[m], qb1[v * 3 + m], val);
#pragma unroll
    for (int m = 0; m < 5; ++m) val = fmaf(sph2[m], qb2[v * 5 + m], val);
    float* og = out + (long)batch[n] * 9;
    atomicAdd(&og[((i + 1) % 3) * 3 + ((j + 1) % 3)], val);
  }
}

// ---------------------------------------------------------------------------

extern "C" void kernel_launch(void* const* d_in, const int* in_sizes, int n_in,
                              void* d_out, int out_size, void* d_ws, size_t ws_size,
                              hipStream_t stream) {
  const float* x_scalar = (const float*)d_in[0];
  const float* x_sph    = (const float*)d_in[1];
  const int*   batch    = (const int*)d_in[2];
  const float* W0 = (const float*)d_in[4];
  const float* W1 = (const float*)d_in[5];
  const float* W2 = (const float*)d_in[6];
  const float* A1 = (const float*)d_in[7];
  const float* b1 = (const float*)d_in[8];
  const float* A2 = (const float*)d_in[9];
  const float* b2 = (const float*)d_in[10];
  const float* p0 = (const float*)d_in[11];
  const float* p1 = (const float*)d_in[12];
  const float* p2 = (const float*)d_in[13];
  float* out = (float*)d_out;
  float* ws  = (float*)d_ws;

  const int N = in_sizes[0] / 128;

  hipMemsetAsync(d_out, 0, (size_t)out_size * sizeof(float), stream);
  setup_cg_par<<<12, 128, 0, stream>>>(ws);
  pack_weights<<<(PK_TOTAL + 255) / 256, 256, 0, stream>>>(A1, W0, A2, W1, W2, ws);
  const int blocks = (N + 15) / 16;
  mega_fused<<<blocks, 512, 0, stream>>>(x_scalar, x_sph, batch, b1, b2, p0, p1, p2,
                                         ws, out, N);
}